// Round 1
// baseline (2109.438 us; speedup 1.0000x reference)
//
#include <hip/hip_runtime.h>
#include <hip/hip_bf16.h>
#include <math.h>

// Sizes from the reference
#define EMBC   192
#define HIDC   64
#define NLAY   6
#define IMGC   224
#define FMAPC  56
#define NNODE  3136      // 56*56
#define NBATCH 8
#define BNODES 25088     // NBATCH*NNODE
#define KNNE   8
#define RSQRT2 0.70710678118654752f

__device__ __forceinline__ float sigm(float x){ return 1.0f/(1.0f+__expf(-x)); }

// ---------------- K0: transpose stem_g / (stem_b+pos) to [n][c] ----------------
__global__ void k_tr(const float* __restrict__ g, const float* __restrict__ sb,
                     const float* __restrict__ pe, float* __restrict__ g2,
                     float* __restrict__ pb2){
  int n = blockIdx.x; int c = threadIdx.x;   // grid 3136, block 192
  g2[n*EMBC + c]  = g[c*NNODE + n];
  pb2[n*EMBC + c] = sb[c*NNODE + n] + pe[c*NNODE + n];
}

// ---------------- K1: stem conv (4x4 stride 4) + LN partial sums ----------------
__global__ __launch_bounds__(256) void k_conv(const float* __restrict__ x,
    const float* __restrict__ cw, const float* __restrict__ cb,
    float* __restrict__ y0, float* __restrict__ parts){
  __shared__ float xs[2688];   // 3ci * 4kh * 224
  __shared__ float wsh[9216];  // 192c * 48
  __shared__ float red[512];
  int blk = blockIdx.x; int b = blk / FMAPC; int ph = blk % FMAPC;
  int tid = threadIdx.x;
  for(int t = tid; t < 9216; t += 256) wsh[t] = cw[t];
  for(int t = tid; t < 2688; t += 256){
    int r = t / IMGC; int w = t % IMGC;     // r = ci*4+kh
    int ci = r >> 2, kh = r & 3;
    xs[t] = x[((size_t)(b*3 + ci)*IMGC + (ph*4 + kh))*IMGC + w];
  }
  __syncthreads();
  float s1 = 0.f, s2 = 0.f;
  for(int oi = tid; oi < FMAPC*EMBC; oi += 256){
    int pw = oi / EMBC; int c = oi % EMBC;
    float acc = cb[c];
    const float4* wv4 = (const float4*)(wsh + c*48);
    #pragma unroll
    for(int r = 0; r < 12; ++r){
      float4 xv = *((const float4*)(xs + r*IMGC + pw*4));
      float4 wv = wv4[r];
      acc += xv.x*wv.x + xv.y*wv.y + xv.z*wv.z + xv.w*wv.w;
    }
    y0[((size_t)(b*NNODE + ph*FMAPC + pw))*EMBC + c] = acc;
    s1 += acc; s2 += acc*acc;
  }
  red[tid] = s1; red[256+tid] = s2;
  __syncthreads();
  for(int st = 128; st > 0; st >>= 1){
    if(tid < st){ red[tid] += red[tid+st]; red[256+tid] += red[256+tid+st]; }
    __syncthreads();
  }
  if(tid == 0){ parts[blk*2] = red[0]; parts[blk*2+1] = red[256]; }
}

// ---------------- K2: finalize per-batch LN stats ----------------
__global__ void k_stats(const float* __restrict__ parts, float* __restrict__ stats){
  int b = threadIdx.x;
  if(b < NBATCH){
    float S = 0.f, Q = 0.f;
    for(int j = 0; j < FMAPC; ++j){ S += parts[(b*FMAPC+j)*2]; Q += parts[(b*FMAPC+j)*2+1]; }
    float cnt = (float)(EMBC*NNODE);
    float mu = S/cnt;
    float var = Q/cnt - mu*mu;
    stats[b*2] = mu; stats[b*2+1] = rsqrtf(var + 1e-5f);
  }
}

// ---------------- K3: LN + pos + embed + mvlin_flat(in_W) -> x_mv ----------------
__global__ __launch_bounds__(256) void k_embed(const float* __restrict__ y0,
    const float* __restrict__ stats, const float* __restrict__ g2,
    const float* __restrict__ pb2, const float* __restrict__ inW,
    const float* __restrict__ inb, const float* __restrict__ coords,
    float* __restrict__ xmv){
  __shared__ float Ws[64*193];   // 12352 floats
  __shared__ float fs[192];
  __shared__ float red[256];
  int tid = threadIdx.x;
  for(int t = tid; t < 64*193; t += 256) Ws[t] = inW[t];
  int ch = tid & 63, q = tid >> 6;
  int pend = blockIdx.x*16 + 16;
  for(int p = blockIdx.x*16; p < pend; ++p){
    int b = p / NNODE, n = p % NNODE;
    float mu = stats[b*2], rstd = stats[b*2+1];
    __syncthreads();
    if(tid < EMBC)
      fs[tid] = (y0[(size_t)p*EMBC + tid] - mu)*rstd*g2[n*EMBC+tid] + pb2[n*EMBC+tid];
    __syncthreads();
    float part = 0.f;
    const float* wr = Ws + ch*193 + q*48;
    const float* fr = fs + q*48;
    #pragma unroll 8
    for(int c = 0; c < 48; ++c) part += wr[c]*fr[c];
    red[tid] = part;
    __syncthreads();
    if(q == 0){
      float x0 = inb[ch] + red[ch] + red[64+ch] + red[128+ch] + red[192+ch];
      float wc = Ws[ch*193 + 192];
      float cx = coords[n*2], cy = coords[n*2+1];
      float4 v; v.x = x0; v.y = wc*cx; v.z = wc*cy; v.w = 0.f;
      *((float4*)(xmv + ((size_t)p*64 + ch)*4)) = v;
    }
  }
}

// ---------------- K5: z = mvlin(h, W) (no bias), weights in VGPRs ----------------
__global__ __launch_bounds__(256,1) void k_mvlin(const float* __restrict__ src,
    float* __restrict__ dst, const float* __restrict__ W, int npb){
  __shared__ float xs[256];   // [blade][m]
  int tid = threadIdx.x;
  int ch = tid & 63, bi = tid >> 6;
  int g = (bi==0)?0:((bi==3)?2:1);
  float w[64];
  #pragma unroll
  for(int m = 0; m < 64; ++m) w[m] = W[(ch*64+m)*3 + g];
  int p0 = blockIdx.x * npb;
  for(int p = p0; p < p0 + npb; ++p){
    __syncthreads();
    xs[(tid&3)*64 + (tid>>2)] = src[(size_t)p*256 + tid];
    __syncthreads();
    float acc = 0.f;
    const float4* xv = (const float4*)(xs + bi*64);
    #pragma unroll
    for(int m4 = 0; m4 < 16; ++m4){
      float4 v = xv[m4];
      acc += w[m4*4]*v.x + w[m4*4+1]*v.y + w[m4*4+2]*v.z + w[m4*4+3]*v.w;
    }
    dst[(p*64 + ch)*4 + bi] = acc;
  }
}

// ---------------- K6: per-node edge gating + aggregation ----------------
__global__ __launch_bounds__(256) void k_edge(const float* __restrict__ z,
    const int* __restrict__ cols, const float* __restrict__ eb,
    const float* __restrict__ sa, const float* __restrict__ sb,
    float* __restrict__ agg){
  int tid = threadIdx.x;
  int ch = tid & 63;
  int p = blockIdx.x*4 + (tid >> 6);
  float4 zo = *((const float4*)(z + ((size_t)p*64 + ch)*4));
  float bias = eb[ch];
  float a0 = sa[ch*3], a1 = sa[ch*3+1], a2 = sa[ch*3+2];
  float b0 = sb[ch*3], b1 = sb[ch*3+1], b2 = sb[ch*3+2];
  float4 acc; acc.x = 0.f; acc.y = 0.f; acc.z = 0.f; acc.w = 0.f;
  #pragma unroll
  for(int k = 0; k < KNNE; ++k){
    int c = cols[p*KNNE + k];
    float4 zc = *((const float4*)(z + ((size_t)c*64 + ch)*4));
    float d0 = zo.x - zc.x + bias;
    float d1 = zo.y - zc.y;
    float d2 = zo.z - zc.z;
    float d3 = zo.w - zc.w;
    float g0 = sigm(a0*d0 + b0);
    float g1 = sigm(a1*(d1*d1 + d2*d2) + b1);
    float g2v = sigm(a2*(d3*d3) + b2);
    acc.x += g0*d0; acc.y += g1*d1; acc.z += g1*d2; acc.w += g2v*d3;
  }
  *((float4*)(agg + ((size_t)p*64 + ch)*4)) = acc;
}

// ---------------- K7: nu = mvlin(concat[h,agg], nW, nb) ----------------
__global__ __launch_bounds__(256,1) void k_nu(const float* __restrict__ h,
    const float* __restrict__ agg, float* __restrict__ nu,
    const float* __restrict__ W, const float* __restrict__ nb, int npb){
  __shared__ float xs[512];   // [blade][m 0..127]
  int tid = threadIdx.x;
  int ch = tid & 63, bi = tid >> 6;
  int g = (bi==0)?0:((bi==3)?2:1);
  float w[128];
  #pragma unroll
  for(int m = 0; m < 128; ++m) w[m] = W[(ch*128+m)*3 + g];
  float bias = nb[ch];
  int p0 = blockIdx.x * npb;
  for(int p = p0; p < p0 + npb; ++p){
    __syncthreads();
    { int m = tid >> 2, i = tid & 3;
      xs[i*128 + m]      = h  [(size_t)p*256 + tid];
      xs[i*128 + 64 + m] = agg[(size_t)p*256 + tid]; }
    __syncthreads();
    float acc = (bi==0)? bias : 0.f;
    const float4* xv = (const float4*)(xs + bi*128);
    #pragma unroll
    for(int m4 = 0; m4 < 32; ++m4){
      float4 v = xv[m4];
      acc += w[m4*4]*v.x + w[m4*4+1]*v.y + w[m4*4+2]*v.z + w[m4*4+3]*v.w;
    }
    nu[(p*64 + ch)*4 + bi] = acc;
  }
}

// ---------------- K8: sgp (+ optional mv_silu, + optional residual) ----------------
// mode 0: h = sgp(src)          (input layer)
// mode 1: h = silu(sgp(src))    (layer 0)
// mode 2: h += silu(sgp(src))   (layers 1..5)
__global__ __launch_bounds__(256,1) void k_sgp(const float* __restrict__ src,
    float* __restrict__ h, const float* __restrict__ Wl, const float* __restrict__ bl,
    const float* __restrict__ Wr, const float* __restrict__ na,
    const float* __restrict__ gw, const float* __restrict__ aa,
    const float* __restrict__ ab, int mode, int npb){
  __shared__ float xs[256];
  __shared__ float yrs[320];   // [ch*5 + blade] padded stride
  __shared__ float xrs[320];
  __shared__ float ous[320];
  int tid = threadIdx.x;
  int ch = tid & 63, bi = tid >> 6;
  int g = (bi==0)?0:((bi==3)?2:1);
  float wl[64], wr[64];
  #pragma unroll
  for(int m = 0; m < 64; ++m){ wl[m] = Wl[(ch*64+m)*3+g]; wr[m] = Wr[(ch*64+m)*3+g]; }
  float blv = bl[ch];
  float nav = sigm(na[ch*3 + g]);
  // Cayley-path weights needed by this output blade (derived from 16-entry table)
  float wA, wB, wC, wD = 0.f;
  if(bi==0)      { wA=gw[ch*10+0]; wB=gw[ch*10+3]; wC=gw[ch*10+7]; }
  else if(bi==3) { wA=gw[ch*10+2]; wB=gw[ch*10+6]; wC=gw[ch*10+9]; }
  else           { wA=gw[ch*10+1]; wB=gw[ch*10+4]; wC=gw[ch*10+5]; wD=gw[ch*10+8]; }
  float aav = 0.f, abv = 0.f;
  if(mode != 0){ aav = aa[ch*3+g]; abv = ab[ch*3+g]; }
  int p0 = blockIdx.x * npb;
  for(int p = p0; p < p0 + npb; ++p){
    __syncthreads();
    xs[(tid&3)*64 + (tid>>2)] = src[(size_t)p*256 + tid];
    __syncthreads();
    float accl = (bi==0)? blv : 0.f;
    float accr = 0.f;
    const float4* xv = (const float4*)(xs + bi*64);
    #pragma unroll
    for(int m4 = 0; m4 < 16; ++m4){
      float4 v = xv[m4];
      accl += wl[m4*4]*v.x + wl[m4*4+1]*v.y + wl[m4*4+2]*v.z + wl[m4*4+3]*v.w;
      accr += wr[m4*4]*v.x + wr[m4*4+1]*v.y + wr[m4*4+2]*v.z + wr[m4*4+3]*v.w;
    }
    yrs[ch*5 + bi] = accr;
    __syncthreads();
    float q;
    if(g==0)      { float u = yrs[ch*5+0]; q = u*u; }
    else if(g==1) { float u = yrs[ch*5+1], v2 = yrs[ch*5+2]; q = u*u + v2*v2; }
    else          { float u = yrs[ch*5+3]; q = u*u; }
    float nn = sqrtf(q + 1e-12f);
    float dd = nav*(nn - 1.f) + 1.f;
    float xr = accr/(dd + 1e-6f);
    xrs[ch*5 + bi] = xr;
    __syncthreads();
    float x0 = xs[ch], x1 = xs[64+ch], x2 = xs[128+ch], x3 = xs[192+ch];
    float xr0 = xrs[ch*5+0], xr1 = xrs[ch*5+1], xr2 = xrs[ch*5+2], xr3 = xrs[ch*5+3];
    float gp;
    if(bi==0)      gp = wA*x0*xr0 + wB*(x1*xr1 + x2*xr2) + wC*x3*xr3;
    else if(bi==1) gp = wA*x0*xr1 + wB*x1*xr0 - wC*x2*xr3 - wD*x3*xr2;
    else if(bi==2) gp = wA*x0*xr2 + wB*x2*xr0 + wC*x1*xr3 + wD*x3*xr1;
    else           gp = wA*x0*xr3 + wB*(x1*xr2 - x2*xr1) - wC*x3*xr0;
    float o = (accl + gp)*RSQRT2;
    int idx = (p*64 + ch)*4 + bi;
    if(mode == 0){
      h[idx] = o;
    } else {
      ous[ch*5 + bi] = o;
      __syncthreads();
      float inv;
      if(g==0)      inv = ous[ch*5+0];
      else if(g==1) { float u = ous[ch*5+1], v2 = ous[ch*5+2]; inv = u*u + v2*v2; }
      else          { float u = ous[ch*5+3]; inv = u*u; }
      float gate = sigm(aav*inv + abv);
      float val = gate*o;
      if(mode == 2) val += h[idx];
      h[idx] = val;
    }
  }
}

// ---------------- K9: head projection (blade 0) + per-node LN ----------------
__global__ __launch_bounds__(256) void k_head(const float* __restrict__ h,
    const float* __restrict__ oW, const float* __restrict__ ob,
    const float* __restrict__ ong, const float* __restrict__ onb,
    float* __restrict__ s, int npb){
  __shared__ float Ws[EMBC*65];   // padded stride 65 -> conflict-free
  __shared__ float hx[64];
  __shared__ float r1[256];
  __shared__ float r2[256];
  int tid = threadIdx.x;
  for(int t = tid; t < EMBC*64; t += 256){ int c = t >> 6, m = t & 63; Ws[c*65+m] = oW[t]; }
  int p0 = blockIdx.x * npb;
  for(int p = p0; p < p0 + npb; ++p){
    __syncthreads();
    if(tid < 64) hx[tid] = h[((size_t)p*64 + tid)*4];
    __syncthreads();
    float acc = 0.f;
    if(tid < EMBC){
      acc = ob[tid];
      const float* wr = Ws + tid*65;
      #pragma unroll 8
      for(int m = 0; m < 64; ++m) acc += wr[m]*hx[m];
    }
    r1[tid] = (tid < EMBC)? acc : 0.f;
    r2[tid] = (tid < EMBC)? acc*acc : 0.f;
    __syncthreads();
    for(int st = 128; st > 0; st >>= 1){
      if(tid < st){ r1[tid] += r1[tid+st]; r2[tid] += r2[tid+st]; }
      __syncthreads();
    }
    float mu = r1[0]*(1.0f/EMBC);
    float var = r2[0]*(1.0f/EMBC) - mu*mu;
    float rstd = rsqrtf(var + 1e-5f);
    if(tid < EMBC) s[(size_t)p*EMBC + tid] = (acc - mu)*rstd*ong[tid] + onb[tid];
  }
}

// ---------------- K10: pooling (two-stage, deterministic) ----------------
__global__ void k_pool1(const float* __restrict__ s, float* __restrict__ pp){
  int blk = blockIdx.x;            // 256 = 8 b * 32 chunks
  int b = blk >> 5, chunk = blk & 31;
  int c = threadIdx.x;             // 192
  float acc = 0.f;
  int n0 = chunk*98;
  for(int j = 0; j < 98; ++j) acc += s[((size_t)(b*NNODE + n0 + j))*EMBC + c];
  pp[(size_t)blk*EMBC + c] = acc;
}
__global__ void k_pool2(const float* __restrict__ pp, float* __restrict__ pooled){
  int b = blockIdx.x; int c = threadIdx.x;
  float acc = 0.f;
  for(int j = 0; j < 32; ++j) acc += pp[((size_t)(b*32 + j))*EMBC + c];
  pooled[b*EMBC + c] = acc * (1.0f/NNODE);
}

// ---------------- K11: classifier ----------------
__global__ void k_cls(const float* __restrict__ pooled, const float* __restrict__ cW,
                      const float* __restrict__ cb, float* __restrict__ out){
  int tid = threadIdx.x;
  if(tid < NBATCH*10){
    int b = tid/10, k = tid%10;
    float acc = cb[k];
    for(int c = 0; c < EMBC; ++c) acc += pooled[b*EMBC + c]*cW[k*EMBC + c];
    out[tid] = acc;
  }
}

extern "C" void kernel_launch(void* const* d_in, const int* in_sizes, int n_in,
                              void* d_out, int out_size, void* d_ws, size_t ws_size,
                              hipStream_t stream){
  const float* x      = (const float*)d_in[0];
  const float* conv_w = (const float*)d_in[1];
  const float* conv_b = (const float*)d_in[2];
  const float* stem_g = (const float*)d_in[3];
  const float* stem_b = (const float*)d_in[4];
  const float* pos_e  = (const float*)d_in[5];
  const float* coords = (const float*)d_in[6];
  const float* inW    = (const float*)d_in[7];
  const float* inb    = (const float*)d_in[8];
  const float* inWl   = (const float*)d_in[9];
  const float* inbl   = (const float*)d_in[10];
  const float* inWr   = (const float*)d_in[11];
  const float* inna   = (const float*)d_in[12];
  const float* ingw   = (const float*)d_in[13];
  const float* eg_eW  = (const float*)d_in[14];
  const float* eg_eb  = (const float*)d_in[15];
  const float* eg_sa  = (const float*)d_in[16];
  const float* eg_sb  = (const float*)d_in[17];
  const float* eg_nW  = (const float*)d_in[18];
  const float* eg_nb  = (const float*)d_in[19];
  const float* eg_Wl  = (const float*)d_in[20];
  const float* eg_bl  = (const float*)d_in[21];
  const float* eg_Wr  = (const float*)d_in[22];
  const float* eg_na  = (const float*)d_in[23];
  const float* eg_gw  = (const float*)d_in[24];
  const float* eg_aa  = (const float*)d_in[25];
  const float* eg_ab  = (const float*)d_in[26];
  const float* outW   = (const float*)d_in[27];
  const float* outb   = (const float*)d_in[28];
  const float* ong    = (const float*)d_in[29];
  const float* onb    = (const float*)d_in[30];
  const float* clsW   = (const float*)d_in[31];
  const float* clsb   = (const float*)d_in[32];
  const int*   cols   = (const int*)d_in[34];   // rows[p*8+k] == p by construction

  float* ws = (float*)d_ws;
  size_t off = 0;
  float* hbuf  = ws + off; off += (size_t)BNODES*256;   // h  [p][64][4]
  float* zbuf  = ws + off; off += (size_t)BNODES*256;   // z / x_mv / nu / s
  float* abuf  = ws + off; off += (size_t)BNODES*256;   // agg
  float* g2    = ws + off; off += (size_t)NNODE*EMBC;
  float* pb2   = ws + off; off += (size_t)NNODE*EMBC;
  float* y0    = ws + off; off += (size_t)BNODES*EMBC;
  float* parts = ws + off; off += 896;
  float* stats = ws + off; off += 16;
  float* pp    = ws + off; off += 256*EMBC;
  float* pooled= ws + off; off += NBATCH*EMBC;
  // total ~25.3M floats (~101.4 MB) — must fit ws_size

  k_tr   <<<NNODE, 192, 0, stream>>>(stem_g, stem_b, pos_e, g2, pb2);
  k_conv <<<NBATCH*FMAPC, 256, 0, stream>>>(x, conv_w, conv_b, y0, parts);
  k_stats<<<1, 64, 0, stream>>>(parts, stats);
  k_embed<<<BNODES/16, 256, 0, stream>>>(y0, stats, g2, pb2, inW, inb, coords, zbuf);
  k_sgp  <<<512, 256, 0, stream>>>(zbuf, hbuf, inWl, inbl, inWr, inna, ingw,
                                   (const float*)nullptr, (const float*)nullptr, 0, 49);
  for(int l = 0; l < NLAY; ++l){
    k_mvlin<<<512, 256, 0, stream>>>(hbuf, zbuf, eg_eW + (size_t)l*12288, 49);
    k_edge <<<BNODES/4, 256, 0, stream>>>(zbuf, cols, eg_eb + l*64,
                                          eg_sa + l*192, eg_sb + l*192, abuf);
    k_nu   <<<512, 256, 0, stream>>>(hbuf, abuf, zbuf, eg_nW + (size_t)l*24576,
                                     eg_nb + l*64, 49);
    k_sgp  <<<512, 256, 0, stream>>>(zbuf, hbuf, eg_Wl + (size_t)l*12288, eg_bl + l*64,
                                     eg_Wr + (size_t)l*12288, eg_na + l*192,
                                     eg_gw + l*640, eg_aa + l*192, eg_ab + l*192,
                                     (l==0)?1:2, 49);
  }
  k_head <<<256, 256, 0, stream>>>(hbuf, outW, outb, ong, onb, zbuf, 98);
  k_pool1<<<256, 192, 0, stream>>>(zbuf, pp);
  k_pool2<<<8, 192, 0, stream>>>(pp, pooled);
  k_cls  <<<1, 128, 0, stream>>>(pooled, clsW, clsb, (float*)d_out);
}

// Round 2
// 1838.648 us; speedup vs baseline: 1.1473x; 1.1473x over previous
//
#include <hip/hip_runtime.h>
#include <hip/hip_bf16.h>
#include <math.h>

// Sizes from the reference
#define EMBC   192
#define HIDC   64
#define NLAY   6
#define IMGC   224
#define FMAPC  56
#define NNODE  3136      // 56*56
#define NBATCH 8
#define BNODES 25088     // NBATCH*NNODE
#define KNNE   8
#define RSQRT2 0.70710678118654752f

__device__ __forceinline__ float sigm(float x){ return 1.0f/(1.0f+__expf(-x)); }

// ---------------- K0: transpose stem_g / (stem_b+pos) to [n][c] ----------------
__global__ void k_tr(const float* __restrict__ g, const float* __restrict__ sb,
                     const float* __restrict__ pe, float* __restrict__ g2,
                     float* __restrict__ pb2){
  int n = blockIdx.x; int c = threadIdx.x;   // grid 3136, block 192
  g2[n*EMBC + c]  = g[c*NNODE + n];
  pb2[n*EMBC + c] = sb[c*NNODE + n] + pe[c*NNODE + n];
}

// ---------------- K1: stem conv (4x4 stride 4) + LN partial sums ----------------
__global__ __launch_bounds__(256) void k_conv(const float* __restrict__ x,
    const float* __restrict__ cw, const float* __restrict__ cb,
    float* __restrict__ y0, float* __restrict__ parts){
  __shared__ float xs[2688];   // 3ci * 4kh * 224
  __shared__ float wsh[9216];  // 192c * 48
  __shared__ float red[512];
  int blk = blockIdx.x; int b = blk / FMAPC; int ph = blk % FMAPC;
  int tid = threadIdx.x;
  for(int t = tid; t < 9216; t += 256) wsh[t] = cw[t];
  for(int t = tid; t < 2688; t += 256){
    int r = t / IMGC; int w = t % IMGC;     // r = ci*4+kh
    int ci = r >> 2, kh = r & 3;
    xs[t] = x[((size_t)(b*3 + ci)*IMGC + (ph*4 + kh))*IMGC + w];
  }
  __syncthreads();
  float s1 = 0.f, s2 = 0.f;
  for(int oi = tid; oi < FMAPC*EMBC; oi += 256){
    int pw = oi / EMBC; int c = oi % EMBC;
    float acc = cb[c];
    const float4* wv4 = (const float4*)(wsh + c*48);
    #pragma unroll
    for(int r = 0; r < 12; ++r){
      float4 xv = *((const float4*)(xs + r*IMGC + pw*4));
      float4 wv = wv4[r];
      acc += xv.x*wv.x + xv.y*wv.y + xv.z*wv.z + xv.w*wv.w;
    }
    y0[((size_t)(b*NNODE + ph*FMAPC + pw))*EMBC + c] = acc;
    s1 += acc; s2 += acc*acc;
  }
  red[tid] = s1; red[256+tid] = s2;
  __syncthreads();
  for(int st = 128; st > 0; st >>= 1){
    if(tid < st){ red[tid] += red[tid+st]; red[256+tid] += red[256+tid+st]; }
    __syncthreads();
  }
  if(tid == 0){ parts[blk*2] = red[0]; parts[blk*2+1] = red[256]; }
}

// ---------------- K2: finalize per-batch LN stats ----------------
__global__ void k_stats(const float* __restrict__ parts, float* __restrict__ stats){
  int b = threadIdx.x;
  if(b < NBATCH){
    float S = 0.f, Q = 0.f;
    for(int j = 0; j < FMAPC; ++j){ S += parts[(b*FMAPC+j)*2]; Q += parts[(b*FMAPC+j)*2+1]; }
    float cnt = (float)(EMBC*NNODE);
    float mu = S/cnt;
    float var = Q/cnt - mu*mu;
    stats[b*2] = mu; stats[b*2+1] = rsqrtf(var + 1e-5f);
  }
}

// ---------------- K3: LN + pos + embed + mvlin_flat(in_W) -> x_mv ----------------
__global__ __launch_bounds__(256) void k_embed(const float* __restrict__ y0,
    const float* __restrict__ stats, const float* __restrict__ g2,
    const float* __restrict__ pb2, const float* __restrict__ inW,
    const float* __restrict__ inb, const float* __restrict__ coords,
    float* __restrict__ xmv){
  __shared__ float Ws[64*193];   // 12352 floats
  __shared__ float fs[192];
  __shared__ float red[256];
  int tid = threadIdx.x;
  for(int t = tid; t < 64*193; t += 256) Ws[t] = inW[t];
  int ch = tid & 63, q = tid >> 6;
  int pend = blockIdx.x*16 + 16;
  for(int p = blockIdx.x*16; p < pend; ++p){
    int b = p / NNODE, n = p % NNODE;
    float mu = stats[b*2], rstd = stats[b*2+1];
    __syncthreads();
    if(tid < EMBC)
      fs[tid] = (y0[(size_t)p*EMBC + tid] - mu)*rstd*g2[n*EMBC+tid] + pb2[n*EMBC+tid];
    __syncthreads();
    float part = 0.f;
    const float* wr = Ws + ch*193 + q*48;
    const float* fr = fs + q*48;
    #pragma unroll 8
    for(int c = 0; c < 48; ++c) part += wr[c]*fr[c];
    red[tid] = part;
    __syncthreads();
    if(q == 0){
      float x0 = inb[ch] + red[ch] + red[64+ch] + red[128+ch] + red[192+ch];
      float wc = Ws[ch*193 + 192];
      float cx = coords[n*2], cy = coords[n*2+1];
      float4 v; v.x = x0; v.y = wc*cx; v.z = wc*cy; v.w = 0.f;
      *((float4*)(xmv + ((size_t)p*64 + ch)*4)) = v;
    }
  }
}

// ---------------- K5: z = mvlin(h, W) (no bias), weights in VGPRs ----------------
__global__ __launch_bounds__(256,1) void k_mvlin(const float* __restrict__ src,
    float* __restrict__ dst, const float* __restrict__ W, int npb){
  __shared__ float xs[256];   // [blade][m]
  int tid = threadIdx.x;
  int ch = tid & 63, bi = tid >> 6;
  int g = (bi==0)?0:((bi==3)?2:1);
  float w[64];
  #pragma unroll
  for(int m = 0; m < 64; ++m) w[m] = W[(ch*64+m)*3 + g];
  int p0 = blockIdx.x * npb;
  for(int p = p0; p < p0 + npb; ++p){
    __syncthreads();
    xs[(tid&3)*64 + (tid>>2)] = src[(size_t)p*256 + tid];
    __syncthreads();
    float acc = 0.f;
    const float4* xv = (const float4*)(xs + bi*64);
    #pragma unroll
    for(int m4 = 0; m4 < 16; ++m4){
      float4 v = xv[m4];
      acc += w[m4*4]*v.x + w[m4*4+1]*v.y + w[m4*4+2]*v.z + w[m4*4+3]*v.w;
    }
    dst[(p*64 + ch)*4 + bi] = acc;
  }
}

// ---------------- K6: per-node edge gating + aggregation ----------------
__global__ __launch_bounds__(256) void k_edge(const float* __restrict__ z,
    const int* __restrict__ cols, const float* __restrict__ eb,
    const float* __restrict__ sa, const float* __restrict__ sb,
    float* __restrict__ agg){
  int tid = threadIdx.x;
  int ch = tid & 63;
  int p = blockIdx.x*4 + (tid >> 6);
  float4 zo = *((const float4*)(z + ((size_t)p*64 + ch)*4));
  float bias = eb[ch];
  float a0 = sa[ch*3], a1 = sa[ch*3+1], a2 = sa[ch*3+2];
  float b0 = sb[ch*3], b1 = sb[ch*3+1], b2 = sb[ch*3+2];
  float4 acc; acc.x = 0.f; acc.y = 0.f; acc.z = 0.f; acc.w = 0.f;
  #pragma unroll
  for(int k = 0; k < KNNE; ++k){
    int c = cols[p*KNNE + k];
    float4 zc = *((const float4*)(z + ((size_t)c*64 + ch)*4));
    float d0 = zo.x - zc.x + bias;
    float d1 = zo.y - zc.y;
    float d2 = zo.z - zc.z;
    float d3 = zo.w - zc.w;
    float g0 = sigm(a0*d0 + b0);
    float g1 = sigm(a1*(d1*d1 + d2*d2) + b1);
    float g2v = sigm(a2*(d3*d3) + b2);
    acc.x += g0*d0; acc.y += g1*d1; acc.z += g1*d2; acc.w += g2v*d3;
  }
  *((float4*)(agg + ((size_t)p*64 + ch)*4)) = acc;
}

// ---------------- K7: nu = mvlin(concat[h,agg], nW, nb) -- 512 thr, K split ----------------
__global__ __launch_bounds__(512,1) void k_nu(const float* __restrict__ h,
    const float* __restrict__ agg, float* __restrict__ nu,
    const float* __restrict__ W, const float* __restrict__ nb, int npb){
  __shared__ float xs[512];   // [blade][m 0..127]
  __shared__ float ps[512];   // partials [half][bi][ch]
  int tid = threadIdx.x;
  int ch = tid & 63, bi = (tid >> 6) & 3, half = tid >> 8;
  int g = (bi==0)?0:((bi==3)?2:1);
  float w[64];
  #pragma unroll
  for(int m = 0; m < 64; ++m) w[m] = W[(ch*128 + half*64 + m)*3 + g];
  float bias = nb[ch];
  int p0 = blockIdx.x * npb;
  for(int p = p0; p < p0 + npb; ++p){
    __syncthreads();
    if(tid < 256){
      int m = tid >> 2, i = tid & 3;
      xs[i*128 + m]      = h  [(size_t)p*256 + tid];
      xs[i*128 + 64 + m] = agg[(size_t)p*256 + tid];
    }
    __syncthreads();
    float acc = 0.f;
    const float4* xv = (const float4*)(xs + bi*128 + half*64);
    #pragma unroll
    for(int m4 = 0; m4 < 16; ++m4){
      float4 v = xv[m4];
      acc += w[m4*4]*v.x + w[m4*4+1]*v.y + w[m4*4+2]*v.z + w[m4*4+3]*v.w;
    }
    ps[tid] = acc;
    __syncthreads();
    if(tid < 256){
      float a = ps[tid] + ps[tid + 256] + ((bi==0)? bias : 0.f);
      nu[(p*64 + ch)*4 + bi] = a;
    }
  }
}

// ---------------- K8: sgp (+ optional mv_silu, + optional residual) -- 512 thr ----------------
// half 0 computes Wl matmul + epilogue; half 1 computes Wr matmul + normalize.
// mode 0: h = sgp(src) ; mode 1: h = silu(sgp(src)) ; mode 2: h += silu(sgp(src))
__global__ __launch_bounds__(512,1) void k_sgp(const float* __restrict__ src,
    float* __restrict__ h, const float* __restrict__ Wl, const float* __restrict__ bl,
    const float* __restrict__ Wr, const float* __restrict__ na,
    const float* __restrict__ gw, const float* __restrict__ aa,
    const float* __restrict__ ab, int mode, int npb){
  __shared__ float xs[256];
  __shared__ float yrs[320];   // raw Wr output [ch*5+bi]
  __shared__ float xrs[320];   // normalized
  __shared__ float ous[320];   // sgp output (pre-silu)
  int tid = threadIdx.x;
  int ch = tid & 63, bi = (tid >> 6) & 3, half = tid >> 8;
  int g = (bi==0)?0:((bi==3)?2:1);
  const float* Wsel = half ? Wr : Wl;
  float w[64];
  #pragma unroll
  for(int m = 0; m < 64; ++m) w[m] = Wsel[(ch*64+m)*3 + g];
  float blv = bl[ch];
  float nav = sigm(na[ch*3 + g]);
  float wA, wB, wC, wD = 0.f;
  if(bi==0)      { wA=gw[ch*10+0]; wB=gw[ch*10+3]; wC=gw[ch*10+7]; }
  else if(bi==3) { wA=gw[ch*10+2]; wB=gw[ch*10+6]; wC=gw[ch*10+9]; }
  else           { wA=gw[ch*10+1]; wB=gw[ch*10+4]; wC=gw[ch*10+5]; wD=gw[ch*10+8]; }
  float aav = 0.f, abv = 0.f;
  if(mode != 0){ aav = aa[ch*3+g]; abv = ab[ch*3+g]; }
  int p0 = blockIdx.x * npb;
  for(int p = p0; p < p0 + npb; ++p){
    __syncthreads();
    if(tid < 256) xs[(tid&3)*64 + (tid>>2)] = src[(size_t)p*256 + tid];
    __syncthreads();
    float acc = (half==0 && bi==0)? blv : 0.f;
    const float4* xv = (const float4*)(xs + bi*64);
    #pragma unroll
    for(int m4 = 0; m4 < 16; ++m4){
      float4 v = xv[m4];
      acc += w[m4*4]*v.x + w[m4*4+1]*v.y + w[m4*4+2]*v.z + w[m4*4+3]*v.w;
    }
    if(half == 1) yrs[ch*5 + bi] = acc;
    __syncthreads();
    if(half == 1){
      float q;
      if(g==0)      { q = acc*acc; }
      else if(g==1) { float u = yrs[ch*5+1], v2 = yrs[ch*5+2]; q = u*u + v2*v2; }
      else          { q = acc*acc; }
      float nn = sqrtf(q + 1e-12f);
      float dd = nav*(nn - 1.f) + 1.f;
      xrs[ch*5 + bi] = acc/(dd + 1e-6f);
    }
    __syncthreads();
    int idx = (p*64 + ch)*4 + bi;
    float o = 0.f;
    if(half == 0){
      float x0 = xs[ch], x1 = xs[64+ch], x2 = xs[128+ch], x3 = xs[192+ch];
      float xr0 = xrs[ch*5+0], xr1 = xrs[ch*5+1], xr2 = xrs[ch*5+2], xr3 = xrs[ch*5+3];
      float gp;
      if(bi==0)      gp = wA*x0*xr0 + wB*(x1*xr1 + x2*xr2) + wC*x3*xr3;
      else if(bi==1) gp = wA*x0*xr1 + wB*x1*xr0 - wC*x2*xr3 - wD*x3*xr2;
      else if(bi==2) gp = wA*x0*xr2 + wB*x2*xr0 + wC*x1*xr3 + wD*x3*xr1;
      else           gp = wA*x0*xr3 + wB*(x1*xr2 - x2*xr1) - wC*x3*xr0;
      o = (acc + gp)*RSQRT2;
      if(mode == 0) h[idx] = o;
      else ous[ch*5 + bi] = o;
    }
    if(mode != 0){
      __syncthreads();
      if(half == 0){
        float inv;
        if(g==0)      inv = ous[ch*5+0];
        else if(g==1) { float u = ous[ch*5+1], v2 = ous[ch*5+2]; inv = u*u + v2*v2; }
        else          { float u = ous[ch*5+3]; inv = u*u; }
        float gate = sigm(aav*inv + abv);
        float val = gate*o;
        if(mode == 2) val += h[idx];
        h[idx] = val;
      }
    }
  }
}

// ---------------- K9: head projection (blade 0) + per-node LN -- 192 thr ----------------
__global__ __launch_bounds__(192) void k_head(const float* __restrict__ h,
    const float* __restrict__ oW, const float* __restrict__ ob,
    const float* __restrict__ ong, const float* __restrict__ onb,
    float* __restrict__ s, int npb){
  __shared__ float hx[64];
  __shared__ float r[6];
  int tid = threadIdx.x; int wv = tid >> 6; int ln = tid & 63;
  float w[64];
  #pragma unroll
  for(int m = 0; m < 64; ++m) w[m] = oW[tid*64 + m];
  float obv = ob[tid], ongv = ong[tid], onbv = onb[tid];
  int p0 = blockIdx.x * npb;
  for(int p = p0; p < p0 + npb; ++p){
    __syncthreads();
    if(tid < 64) hx[tid] = h[((size_t)p*64 + tid)*4];
    __syncthreads();
    float acc = obv;
    const float4* hv = (const float4*)hx;
    #pragma unroll
    for(int m4 = 0; m4 < 16; ++m4){
      float4 v = hv[m4];
      acc += w[m4*4]*v.x + w[m4*4+1]*v.y + w[m4*4+2]*v.z + w[m4*4+3]*v.w;
    }
    float s1 = acc, s2 = acc*acc;
    #pragma unroll
    for(int off = 32; off > 0; off >>= 1){
      s1 += __shfl_down(s1, off);
      s2 += __shfl_down(s2, off);
    }
    if(ln == 0){ r[wv] = s1; r[3+wv] = s2; }
    __syncthreads();
    float S = r[0]+r[1]+r[2], Q = r[3]+r[4]+r[5];
    float mu = S*(1.0f/EMBC);
    float var = Q*(1.0f/EMBC) - mu*mu;
    float rstd = rsqrtf(var + 1e-5f);
    s[(size_t)p*EMBC + tid] = (acc - mu)*rstd*ongv + onbv;
  }
}

// ---------------- K10: pooling (two-stage, deterministic) ----------------
__global__ void k_pool1(const float* __restrict__ s, float* __restrict__ pp){
  int blk = blockIdx.x;            // 256 = 8 b * 32 chunks
  int b = blk >> 5, chunk = blk & 31;
  int c = threadIdx.x;             // 192
  float acc = 0.f;
  int n0 = chunk*98;
  for(int j = 0; j < 98; ++j) acc += s[((size_t)(b*NNODE + n0 + j))*EMBC + c];
  pp[(size_t)blk*EMBC + c] = acc;
}
__global__ void k_pool2(const float* __restrict__ pp, float* __restrict__ pooled){
  int b = blockIdx.x; int c = threadIdx.x;
  float acc = 0.f;
  for(int j = 0; j < 32; ++j) acc += pp[((size_t)(b*32 + j))*EMBC + c];
  pooled[b*EMBC + c] = acc * (1.0f/NNODE);
}

// ---------------- K11: classifier ----------------
__global__ void k_cls(const float* __restrict__ pooled, const float* __restrict__ cW,
                      const float* __restrict__ cb, float* __restrict__ out){
  int tid = threadIdx.x;
  if(tid < NBATCH*10){
    int b = tid/10, k = tid%10;
    float acc = cb[k];
    for(int c = 0; c < EMBC; ++c) acc += pooled[b*EMBC + c]*cW[k*EMBC + c];
    out[tid] = acc;
  }
}

extern "C" void kernel_launch(void* const* d_in, const int* in_sizes, int n_in,
                              void* d_out, int out_size, void* d_ws, size_t ws_size,
                              hipStream_t stream){
  const float* x      = (const float*)d_in[0];
  const float* conv_w = (const float*)d_in[1];
  const float* conv_b = (const float*)d_in[2];
  const float* stem_g = (const float*)d_in[3];
  const float* stem_b = (const float*)d_in[4];
  const float* pos_e  = (const float*)d_in[5];
  const float* coords = (const float*)d_in[6];
  const float* inW    = (const float*)d_in[7];
  const float* inb    = (const float*)d_in[8];
  const float* inWl   = (const float*)d_in[9];
  const float* inbl   = (const float*)d_in[10];
  const float* inWr   = (const float*)d_in[11];
  const float* inna   = (const float*)d_in[12];
  const float* ingw   = (const float*)d_in[13];
  const float* eg_eW  = (const float*)d_in[14];
  const float* eg_eb  = (const float*)d_in[15];
  const float* eg_sa  = (const float*)d_in[16];
  const float* eg_sb  = (const float*)d_in[17];
  const float* eg_nW  = (const float*)d_in[18];
  const float* eg_nb  = (const float*)d_in[19];
  const float* eg_Wl  = (const float*)d_in[20];
  const float* eg_bl  = (const float*)d_in[21];
  const float* eg_Wr  = (const float*)d_in[22];
  const float* eg_na  = (const float*)d_in[23];
  const float* eg_gw  = (const float*)d_in[24];
  const float* eg_aa  = (const float*)d_in[25];
  const float* eg_ab  = (const float*)d_in[26];
  const float* outW   = (const float*)d_in[27];
  const float* outb   = (const float*)d_in[28];
  const float* ong    = (const float*)d_in[29];
  const float* onb    = (const float*)d_in[30];
  const float* clsW   = (const float*)d_in[31];
  const float* clsb   = (const float*)d_in[32];
  const int*   cols   = (const int*)d_in[34];   // rows[p*8+k] == p by construction

  float* ws = (float*)d_ws;
  size_t off = 0;
  float* hbuf  = ws + off; off += (size_t)BNODES*256;   // h  [p][64][4]
  float* zbuf  = ws + off; off += (size_t)BNODES*256;   // z / x_mv / nu / s
  float* abuf  = ws + off; off += (size_t)BNODES*256;   // agg
  float* g2    = ws + off; off += (size_t)NNODE*EMBC;
  float* pb2   = ws + off; off += (size_t)NNODE*EMBC;
  float* y0    = ws + off; off += (size_t)BNODES*EMBC;
  float* parts = ws + off; off += 896;
  float* stats = ws + off; off += 16;
  float* pp    = ws + off; off += 256*EMBC;
  float* pooled= ws + off; off += NBATCH*EMBC;

  k_tr   <<<NNODE, 192, 0, stream>>>(stem_g, stem_b, pos_e, g2, pb2);
  k_conv <<<NBATCH*FMAPC, 256, 0, stream>>>(x, conv_w, conv_b, y0, parts);
  k_stats<<<1, 64, 0, stream>>>(parts, stats);
  k_embed<<<BNODES/16, 256, 0, stream>>>(y0, stats, g2, pb2, inW, inb, coords, zbuf);
  k_sgp  <<<512, 512, 0, stream>>>(zbuf, hbuf, inWl, inbl, inWr, inna, ingw,
                                   (const float*)nullptr, (const float*)nullptr, 0, 49);
  for(int l = 0; l < NLAY; ++l){
    k_mvlin<<<512, 256, 0, stream>>>(hbuf, zbuf, eg_eW + (size_t)l*12288, 49);
    k_edge <<<BNODES/4, 256, 0, stream>>>(zbuf, cols, eg_eb + l*64,
                                          eg_sa + l*192, eg_sb + l*192, abuf);
    k_nu   <<<512, 512, 0, stream>>>(hbuf, abuf, zbuf, eg_nW + (size_t)l*24576,
                                     eg_nb + l*64, 49);
    k_sgp  <<<512, 512, 0, stream>>>(zbuf, hbuf, eg_Wl + (size_t)l*12288, eg_bl + l*64,
                                     eg_Wr + (size_t)l*12288, eg_na + l*192,
                                     eg_gw + l*640, eg_aa + l*192, eg_ab + l*192,
                                     (l==0)?1:2, 49);
  }
  k_head <<<1568, 192, 0, stream>>>(hbuf, outW, outb, ong, onb, zbuf, 16);
  k_pool1<<<256, 192, 0, stream>>>(zbuf, pp);
  k_pool2<<<8, 192, 0, stream>>>(pp, pooled);
  k_cls  <<<1, 128, 0, stream>>>(pooled, clsW, clsb, (float*)d_out);
}